// Round 1
// baseline (430.614 us; speedup 1.0000x reference)
//
#include <hip/hip_runtime.h>

// HausdorffDTLoss: exact separable EDT (fg & bg) per image, then
// mean((pred-target)^2 * (pred_dt^2 + target_dt^2)).
// Key identity: g[i] = min_j f[j]+(i-j)^2 = i^2 + min_j (h[j] - 2*i*j),
// h[j] = f[j] + j^2.  All intermediates are integers < 2^17 -> fp32 exact.

#define BIGV 49153.0f            // 3*128^2 + 1, matches reference BIG
constexpr int NV  = 4194304;     // 2 * 128^3 voxels per image
constexpr int PAD = 65;          // LDS row stride: (j*65+c)%32 = (j+c)%32 -> 2-way max (free)

__global__ void zero_kernel(float* out, int* flags) {
    out[0] = 0.0f;
    flags[0] = 0; flags[1] = 0; flags[2] = 0; flags[3] = 0;
}

// Fused: binarize img -> f_fg/f_bg, EDT pass along z (contiguous axis),
// write sq-dist volumes A (fg) and B (bg). Also per-sample fg_any flag.
__global__ __launch_bounds__(256) void zpass_kernel(const float* __restrict__ img,
                                                    float* __restrict__ A,
                                                    float* __restrict__ Bv,
                                                    int* __restrict__ flag2) {
    __shared__ float lds[128 * PAD];
    const int t   = blockIdx.x;          // 512 tiles: b(2) x x(128) x ychunk(2)
    const int b   = t >> 8;
    const int x   = (t >> 1) & 127;
    const int yc  = t & 1;
    const int base = (b * 128 + x) * 16384 + yc * 8192; // + c*128 + j
    const int tid = threadIdx.x;

    bool any = false;
#pragma unroll
    for (int k = 0; k < 32; ++k) {
        int l = tid + k * 256;           // contiguous 32KB tile
        float v = img[base + l];
        int j = l & 127, cc = l >> 7;    // j = z (transform axis), cc = y-offset
        bool fg = v > 0.5f;
        any |= fg;
        lds[j * PAD + cc] = (fg ? BIGV : 0.0f) + (float)(j * j);   // h_fg
    }
    if (__ballot(any) != 0ULL && (tid & 63) == 0) atomicOr(&flag2[b], 1);
    __syncthreads();

    const int c  = tid & 63;
    const int i0 = (tid >> 6) * 32;
    float accF[32], accB[32], iff[32];
#pragma unroll
    for (int k = 0; k < 32; ++k) { accF[k] = 3e38f; accB[k] = 3e38f; iff[k] = (float)(i0 + k); }
    float jm2 = 0.0f, jf = 0.0f;
    const float* p = lds + c;
#pragma unroll 2
    for (int j = 0; j < 128; ++j) {
        float hf = p[j * PAD];
        float hb = fmaf(2.0f * jf, jf, BIGV) - hf;   // h_bg = BIG + 2j^2 - h_fg (exact)
#pragma unroll
        for (int k = 0; k < 32; ++k) {
            accF[k] = fminf(accF[k], fmaf(jm2, iff[k], hf));
            accB[k] = fminf(accB[k], fmaf(jm2, iff[k], hb));
        }
        jm2 -= 2.0f; jf += 1.0f;
    }

    // transpose fg result through LDS for coalesced store
    __syncthreads();
#pragma unroll
    for (int k = 0; k < 32; ++k) lds[(i0 + k) * PAD + c] = fmaf(iff[k], iff[k], accF[k]);
    __syncthreads();
#pragma unroll
    for (int k = 0; k < 32; ++k) {
        int l = tid + k * 256;
        A[base + l] = lds[(l & 127) * PAD + (l >> 7)];
    }
    __syncthreads();
#pragma unroll
    for (int k = 0; k < 32; ++k) lds[(i0 + k) * PAD + c] = fmaf(iff[k], iff[k], accB[k]);
    __syncthreads();
#pragma unroll
    for (int k = 0; k < 32; ++k) {
        int l = tid + k * 256;
        Bv[base + l] = lds[(l & 127) * PAD + (l >> 7)];
    }
}

// Generic EDT pass along a strided axis (Y: ST=128, X: ST=16384).
// grid.x = 512 tiles, grid.y selects buffer A or B. All global accesses coalesced.
template <int SHIFT, int OSTR, int ST>
__global__ __launch_bounds__(256) void pass_kernel(float* __restrict__ A, float* __restrict__ Bv) {
    __shared__ float lds[128 * PAD];
    float* buf = blockIdx.y ? Bv : A;
    const int t     = blockIdx.x;
    const int outer = t >> SHIFT;
    const int rem   = t & ((1 << SHIFT) - 1);
    const int base  = outer * OSTR + rem * 64;   // + i*ST + c
    const int tid   = threadIdx.x;

#pragma unroll
    for (int k = 0; k < 32; ++k) {
        int l = tid + k * 256;
        int cc = l & 63, j = l >> 6;             // lanes -> consecutive c: coalesced
        float v = buf[base + j * ST + cc];
        lds[j * PAD + cc] = fmaf((float)j, (float)j, v);   // h = f + j^2
    }
    __syncthreads();

    const int c  = tid & 63;
    const int i0 = (tid >> 6) * 32;
    float acc[32], iff[32];
#pragma unroll
    for (int k = 0; k < 32; ++k) { acc[k] = 3e38f; iff[k] = (float)(i0 + k); }
    float jm2 = 0.0f;
    const float* p = lds + c;
#pragma unroll 2
    for (int j = 0; j < 128; ++j) {
        float h = p[j * PAD];
#pragma unroll
        for (int k = 0; k < 32; ++k) acc[k] = fminf(acc[k], fmaf(jm2, iff[k], h));
        jm2 -= 2.0f;
    }
#pragma unroll
    for (int k = 0; k < 32; ++k)
        buf[base + (i0 + k) * ST + c] = fmaf(iff[k], iff[k], acc[k]);  // g = acc + i^2
}

// Accumulate sum((p-t)^2 * guard * (sqrt(A)+sqrt(B))^2) / N for the current image's DT.
__global__ __launch_bounds__(256) void reduce_kernel(const float* __restrict__ pred,
                                                     const float* __restrict__ tgt,
                                                     const float* __restrict__ A,
                                                     const float* __restrict__ Bv,
                                                     const int* __restrict__ flag2,
                                                     float* __restrict__ out) {
    const int tid = threadIdx.x;
    const int stride = gridDim.x * 256;
    float s = 0.0f;
    for (int i = blockIdx.x * 256 + tid; i < NV; i += stride) {
        float pv = pred[i], tv = tgt[i];
        float fld = sqrtf(A[i]) + sqrtf(Bv[i]);
        float g = flag2[i >> 21] ? 1.0f : 0.0f;
        float d = pv - tv;
        s += d * d * fld * fld * g;
    }
#pragma unroll
    for (int off = 32; off > 0; off >>= 1) s += __shfl_down(s, off);
    __shared__ float red[4];
    if ((tid & 63) == 0) red[tid >> 6] = s;
    __syncthreads();
    if (tid == 0) {
        float tot = (red[0] + red[1] + red[2] + red[3]) * (1.0f / 4194304.0f);
        atomicAdd(out, tot);
    }
}

extern "C" void kernel_launch(void* const* d_in, const int* in_sizes, int n_in,
                              void* d_out, int out_size, void* d_ws, size_t ws_size,
                              hipStream_t stream) {
    const float* pred = (const float*)d_in[0];
    const float* tgt  = (const float*)d_in[1];
    float* out = (float*)d_out;
    float* A   = (float*)d_ws;           // 16 MB
    float* Bv  = A + NV;                 // 16 MB
    int* flags = (int*)(Bv + NV);        // 4 ints: [pred_b0, pred_b1, tgt_b0, tgt_b1]

    zero_kernel<<<1, 1, 0, stream>>>(out, flags);
    for (int im = 0; im < 2; ++im) {
        const float* img = im ? tgt : pred;
        zpass_kernel<<<dim3(512), 256, 0, stream>>>(img, A, Bv, flags + 2 * im);
        pass_kernel<1, 16384, 128><<<dim3(512, 2), 256, 0, stream>>>(A, Bv);      // Y pass
        pass_kernel<8, 2097152, 16384><<<dim3(512, 2), 256, 0, stream>>>(A, Bv);  // X pass
        reduce_kernel<<<dim3(1024), 256, 0, stream>>>(pred, tgt, A, Bv, flags + 2 * im, out);
    }
}